// Round 9
// baseline (837.483 us; speedup 1.0000x reference)
//
#include <hip/hip_runtime.h>
#include <hip/hip_bf16.h>
#include <stdint.h>
#include <math.h>

// Problem constants (fixed-shape problem)
#define BQ 4
#define NQ 4096
#define CQ 1024

// ws layout (bytes)
#define WS_CTR      0         // int c123 @0, c3f @4; int refCount[4] @16
#define WS_THRESH   64        // float[4]
#define WS_MASK     256       // uint8[BQ*NQ] = 16384  -> ends 16640
#define WS_REFIDX   17408     // int[BQ*NQ]  = 65536  -> ends 82944
#define WS_MAXV     82944     // float[BQ*NQ]= 65536  -> ends 148480
#define WS_FNH      (4u << 20)               // bf16 hi[BQ*NQ*CQ] = 32 MB
#define WS_FNL      (WS_FNH + (32u << 20))   // bf16 lo[BQ*NQ*CQ] = 32 MB
#define WS_NEED     (WS_FNL + (32u << 20) + (1u << 20))

typedef __bf16 bf16x8 __attribute__((ext_vector_type(8)));
typedef float floatx4 __attribute__((ext_vector_type(4)));

// ---------------------------------------------------------------------------
// K0a: detect mask dtype. Reads only first BQ*NQ bytes (safe under u8/i32/f32).
__global__ void k_detect(const uint8_t* mraw, int* ctr) {
    int c123 = 0, c3f = 0;
    for (int i = threadIdx.x; i < BQ * NQ; i += blockDim.x) {
        uint8_t v = mraw[i];
        int m4 = i & 3;
        if (m4 != 0 && v != 0) c123++;
        if (m4 == 3 && v == 0x3F) c3f++;
    }
    atomicAdd(&ctr[0], c123);
    atomicAdd(&ctr[1], c3f);
}

// K0b: canonicalize mask to uint8 0/1
__global__ void k_canon(const void* mraw, const int* ctr, uint8_t* maskc) {
    int i = blockIdx.x * blockDim.x + threadIdx.x;
    if (i >= BQ * NQ) return;
    int c123 = ctr[0], c3f = ctr[1];
    uint8_t v;
    if (c3f > 64) {
        v = (((const float*)mraw)[i] != 0.0f) ? 1 : 0;
    } else if (c123 == 0) {
        v = (((const int*)mraw)[i] != 0) ? 1 : 0;
    } else {
        v = (((const uint8_t*)mraw)[i] != 0) ? 1 : 0;
    }
    maskc[i] = v;
}

// K0c: compact ref-row indices per batch
__global__ void k_compact(const uint8_t* maskc, int* refCount, int* refIdx) {
    int b = blockIdx.x;
    for (int i = threadIdx.x; i < NQ; i += blockDim.x) {
        if (maskc[b * NQ + i]) {
            int p = atomicAdd(&refCount[b], 1);
            refIdx[b * NQ + p] = i;
        }
    }
}

// K1: fused row norm (f64) + bf16 SPLIT convert: xn = h + l with h = bf16(xn),
// l = bf16(xn - h). h+l represents the f32 normalized value to ~2^-18 rel,
// enabling near-f32-exact Gram via 3 MFMA passes (hh+hl+lh; ll dropped, see K2).
__global__ __launch_bounds__(128) void k_prep(const float* x, __bf16* fnh, __bf16* fnl) {
    int row = blockIdx.x;  // 0..BQ*NQ-1
    int t = threadIdx.x;
    const float4* xr = (const float4*)(x + (long long)row * CQ);
    float4 a = xr[t * 2 + 0];
    float4 c = xr[t * 2 + 1];
    double s = (double)a.x * a.x + (double)a.y * a.y + (double)a.z * a.z + (double)a.w * a.w
             + (double)c.x * c.x + (double)c.y * c.y + (double)c.z * c.z + (double)c.w * c.w;
    __shared__ double red[128];
    __shared__ double invs;
    red[t] = s;
    __syncthreads();
    for (int o = 64; o > 0; o >>= 1) {
        if (t < o) red[t] += red[t + o];
        __syncthreads();
    }
    if (t == 0) invs = 1.0 / fmax(sqrt(red[0]), 1e-12);
    __syncthreads();
    float ir = (float)invs;
    float v[8] = {a.x, a.y, a.z, a.w, c.x, c.y, c.z, c.w};
    bf16x8 h8, l8;
#pragma unroll
    for (int j = 0; j < 8; j++) {
        float xn = v[j] * ir;
        __bf16 h = (__bf16)xn;
        h8[j] = h;
        l8[j] = (__bf16)(xn - (float)h);
    }
    *(bf16x8*)(fnh + (long long)row * CQ + t * 8) = h8;
    *(bf16x8*)(fnl + (long long)row * CQ + t * 8) = l8;
}

// K2: uniform split-bf16 MFMA Gram GEMM, upper-tri 128x128 tiles, 3 passes
// (hh+hl+lh; ll dropped — bounded by 2^-18, two orders below absmax floor).
//
// R8: DOUBLE-BUFFERED LDS with COUNTED vmcnt (T3/T4-minimum). R7 showed the
// 2-barrier loop is ~70% stage/drain-bound (removing 25% of MFMA saved only
// 6%): __syncthreads() emits vmcnt(0) and drains all 8 in-flight
// global_load_lds per step. Now: issue stage(t+1) into buf^1 BEFORE
// compute(t); barrier-1 = s_waitcnt vmcnt(8) (waits only stage(t), the 8
// next-tile loads stay in flight across the barrier) + raw s_barrier;
// barrier-2 = lgkmcnt(0) + raw s_barrier (WAR protection for buf before
// stage(t+2) overwrites it — NO vmcnt, pipeline survives).
// Counted-vmcnt semantics HW-verified (m135); ds_reads are compiler-emitted
// (lgkm deps auto-inserted; rule-18 inline-asm-ds_read hazard not present).
// LDS 64 KB = 2 buffers x [Ah|Al|Bh|Bl] x 8 KB -> 2 blocks/CU.
//
// XCD swizzle: 2112 blocks = 8 x 264 (bijective). LDS swizzle (T2/rule #21):
// linear LDS dest, pre-swizzled global source col, same XOR on the read.
#define GRID_MEGA 2112

#define GLD(src, dst) __builtin_amdgcn_global_load_lds( \
    (const __attribute__((address_space(1))) void*)(src), \
    (__attribute__((address_space(3))) void*)(dst), 16, 0, 0)

__global__ __launch_bounds__(256) void k_mega(const __bf16* fnh, const __bf16* fnl,
                                              float* sim, float* match) {
    // 2 buffers x 16384 bf16 (32 KB): Ah @0, Al @4096, Bh @8192, Bl @12288 (elems)
    __shared__ __align__(16) __bf16 sm[32768];
    const int id = blockIdx.x;
    const int gid = (id & 7) * 264 + (id >> 3);   // XCD-contiguous tri order
    const int b = gid / 528;
    int rem = gid % 528;
    int rT = 0;
    while (rem >= 32 - rT) { rem -= 32 - rT; rT++; }
    const int cT = rT + rem;
    const int rowBase = rT * 128;
    const int colBase = cT * 128;
    const __bf16* baseh = fnh + (long long)b * NQ * CQ;
    const __bf16* basel = fnl + (long long)b * NQ * CQ;

    const int lane = threadIdx.x & 63;
    const int w = threadIdx.x >> 6;
    const int wr = w >> 1, wc = w & 1;
    const int ldrow = lane >> 2;
    // stage-side swizzled source col (elems): ((lane&3)*8) ^ swz(row), row%16 = lane>>2
    const int ldcolS = ((lane & 3) * 8) ^ (((lane >> 3) & 3) << 3);
    // read-side swizzled col (elems): ((lane>>4)*8) ^ swz(row), row%16 = lane&15
    const int co = ((lane >> 4) * 8) ^ (((lane >> 1) & 3) << 3);

    // per-wave staging rows (two 64-row halves) and global element offsets
    const int rs0 = w * 16, rs1 = w * 16 + 64;
    const long long gA0 = (long long)(rowBase + rs0 + ldrow) * CQ + ldcolS;
    const long long gA1 = (long long)(rowBase + rs1 + ldrow) * CQ + ldcolS;
    const long long gB0 = (long long)(colBase + rs0 + ldrow) * CQ + ldcolS;
    const long long gB1 = (long long)(colBase + rs1 + ldrow) * CQ + ldcolS;

    floatx4 acc[4][4] = {};

#define STAGE(k0, buf) do {                                   \
        GLD(baseh + gA0 + (k0), (buf) + 0     + rs0 * 32);    \
        GLD(baseh + gA1 + (k0), (buf) + 0     + rs1 * 32);    \
        GLD(basel + gA0 + (k0), (buf) + 4096  + rs0 * 32);    \
        GLD(basel + gA1 + (k0), (buf) + 4096  + rs1 * 32);    \
        GLD(baseh + gB0 + (k0), (buf) + 8192  + rs0 * 32);    \
        GLD(baseh + gB1 + (k0), (buf) + 8192  + rs1 * 32);    \
        GLD(basel + gB0 + (k0), (buf) + 12288 + rs0 * 32);    \
        GLD(basel + gB1 + (k0), (buf) + 12288 + rs1 * 32);    \
    } while (0)

    STAGE(0, sm);  // prologue: 8 loads in flight
    for (int t = 0; t < 32; t++) {
        __bf16* cur = sm + (t & 1) * 16384;
        if (t < 31) {
            STAGE((t + 1) * 32, sm + ((t + 1) & 1) * 16384);  // 8 more in flight
            asm volatile("s_waitcnt vmcnt(8)" ::: "memory");  // stage(t) done
        } else {
            asm volatile("s_waitcnt vmcnt(0)" ::: "memory");
        }
        __builtin_amdgcn_s_barrier();                         // stage(t) visible

        bf16x8 ah[4], al[4];
#pragma unroll
        for (int i = 0; i < 4; i++) {
            int ra = (wr * 64 + i * 16 + (lane & 15)) * 32 + co;
            ah[i] = *(const bf16x8*)(cur + ra);
            al[i] = *(const bf16x8*)(cur + 4096 + ra);
        }
#pragma unroll
        for (int j = 0; j < 4; j++) {
            int rb = (wc * 64 + j * 16 + (lane & 15)) * 32 + co;
            bf16x8 bh = *(const bf16x8*)(cur + 8192 + rb);
            bf16x8 bl = *(const bf16x8*)(cur + 12288 + rb);
#pragma unroll
            for (int i = 0; i < 4; i++) {
                acc[i][j] = __builtin_amdgcn_mfma_f32_16x16x32_bf16(ah[i], bh, acc[i][j], 0, 0, 0);
                acc[i][j] = __builtin_amdgcn_mfma_f32_16x16x32_bf16(ah[i], bl, acc[i][j], 0, 0, 0);
                acc[i][j] = __builtin_amdgcn_mfma_f32_16x16x32_bf16(al[i], bh, acc[i][j], 0, 0, 0);
            }
        }
        asm volatile("s_waitcnt lgkmcnt(0)" ::: "memory");    // reads of cur done
        __builtin_amdgcn_s_barrier();                         // WAR: buf reusable
    }
#undef STAGE

    // Epilogue A: own tile (rT,cT): sim values + match zeros, all rows.
    float* simb = sim + (long long)b * NQ * NQ;
    float* matb = match + (long long)b * NQ * NQ;
#pragma unroll
    for (int i = 0; i < 4; i++) {
        int r0 = rowBase + wr * 64 + i * 16 + (lane >> 4) * 4;
#pragma unroll
        for (int r = 0; r < 4; r++) {
#pragma unroll
            for (int j = 0; j < 4; j++) {
                int c = colBase + wc * 64 + j * 16 + (lane & 15);
                simb[(long long)(r0 + r) * NQ + c] = acc[i][j][r];
                matb[(long long)(r0 + r) * NQ + c] = 0.0f;
            }
        }
    }
    // Epilogue B: mirror tile (cT,rT) for off-diagonal blocks (bit-identical
    // by operand symmetry). float4 at (c*NQ + r0), 16B aligned.
    if (rT != cT) {
        floatx4 zero4 = {0.0f, 0.0f, 0.0f, 0.0f};
#pragma unroll
        for (int i = 0; i < 4; i++) {
            int r0 = rowBase + wr * 64 + i * 16 + (lane >> 4) * 4;
#pragma unroll
            for (int j = 0; j < 4; j++) {
                int c = colBase + wc * 64 + j * 16 + (lane & 15);
                long long off = (long long)c * NQ + r0;
                *(floatx4*)(simb + off) = acc[i][j];
                *(floatx4*)(matb + off) = zero4;
            }
        }
    }
}

// K3: per ref slot, max over non-ref cols (slot-based, no wasted blocks)
__global__ __launch_bounds__(256) void k_rowmax(const float* sim, const uint8_t* maskc,
                                                const int* refCount, const int* refIdx,
                                                float* maxv) {
    int b = blockIdx.y;
    int cnt = refCount[b];
    __shared__ float red[256];
    for (int slot = blockIdx.x; slot < cnt; slot += gridDim.x) {
        int row = refIdx[b * NQ + slot];
        const float* rp = sim + ((long long)b * NQ + row) * NQ;
        float mx = -INFINITY;
        for (int j = threadIdx.x; j < NQ; j += 256) {
            if (!maskc[b * NQ + j]) mx = fmaxf(mx, rp[j]);
        }
        __syncthreads();
        red[threadIdx.x] = mx;
        __syncthreads();
        for (int o = 128; o > 0; o >>= 1) {
            if (threadIdx.x < o) red[threadIdx.x] = fmaxf(red[threadIdx.x], red[threadIdx.x + o]);
            __syncthreads();
        }
        if (threadIdx.x == 0) maxv[b * NQ + slot] = red[0];
    }
}

// K4: lower median over slots [0,cnt) per batch (O(k^2) rank counting)
__global__ __launch_bounds__(256) void k_median(const float* maxv, const int* refCount,
                                                float* threshv, float* outth) {
    int b = blockIdx.x;
    int k = refCount[b];
    __shared__ float vals[NQ];
    __shared__ float result;
    for (int i = threadIdx.x; i < k; i += blockDim.x) vals[i] = maxv[b * NQ + i];
    __syncthreads();
    int med = (k - 1) / 2;
    for (int t0 = threadIdx.x; t0 < k; t0 += blockDim.x) {
        float v = vals[t0];
        int cl = 0, ce = 0;
        for (int j = 0; j < k; j++) {
            float w = vals[j];
            cl += (w < v) ? 1 : 0;
            ce += (w == v) ? 1 : 0;
        }
        if (cl <= med && med < cl + ce) result = v;  // unique value class; benign race
    }
    __syncthreads();
    if (threadIdx.x == 0) {
        threshv[b] = result;
        outth[b] = result;
    }
}

// K5: match bits for ref rows (background zeros already written by k_mega)
__global__ __launch_bounds__(256) void k_match(const float* sim, const uint8_t* maskc,
                                               const int* refCount, const int* refIdx,
                                               const float* threshv, float* match) {
    int b = blockIdx.y;
    int cnt = refCount[b];
    float th = threshv[b];
    const uint8_t* mb = maskc + b * NQ;
    for (int slot = blockIdx.x; slot < cnt; slot += gridDim.x) {
        int row = refIdx[b * NQ + slot];
        const float* rp = sim + ((long long)b * NQ + row) * NQ;
        float* op = match + ((long long)b * NQ + row) * NQ;
        for (int j = threadIdx.x * 4; j < NQ; j += 256 * 4) {
            float4 s = *(const float4*)(rp + j);
            float4 o;
            o.x = (!mb[j + 0] && s.x > th) ? 1.0f : 0.0f;
            o.y = (!mb[j + 1] && s.y > th) ? 1.0f : 0.0f;
            o.z = (!mb[j + 2] && s.z > th) ? 1.0f : 0.0f;
            o.w = (!mb[j + 3] && s.w > th) ? 1.0f : 0.0f;
            *(float4*)(op + j) = o;
        }
    }
}

extern "C" void kernel_launch(void* const* d_in, const int* in_sizes, int n_in,
                              void* d_out, int out_size, void* d_ws, size_t ws_size,
                              hipStream_t stream) {
    if (in_sizes[0] != BQ * NQ * CQ) return;
    if (ws_size < WS_NEED) return;  // d_ws observed ~2 GiB (poison fills)

    const float* x = (const float*)d_in[0];
    const void* mraw = d_in[1];
    float* out = (float*)d_out;
    uint8_t* ws = (uint8_t*)d_ws;

    int* ctr       = (int*)(ws + WS_CTR);
    int* refCount  = (int*)(ws + 16);
    float* threshv = (float*)(ws + WS_THRESH);
    uint8_t* maskc = ws + WS_MASK;
    int* refIdx    = (int*)(ws + WS_REFIDX);
    float* maxv    = (float*)(ws + WS_MAXV);
    __bf16* fnh    = (__bf16*)(ws + WS_FNH);
    __bf16* fnl    = (__bf16*)(ws + WS_FNL);

    float* match = out;                                // [B,N,N] as 0/1 floats
    float* sim   = out + (long long)BQ * NQ * NQ;      // [B,N,N]
    float* outth = out + 2LL * BQ * NQ * NQ;           // [B]

    hipMemsetAsync(ws, 0, 4096, stream);  // counters

    k_detect<<<1, 256, 0, stream>>>((const uint8_t*)mraw, ctr);
    k_canon<<<(BQ * NQ + 255) / 256, 256, 0, stream>>>(mraw, ctr, maskc);
    k_compact<<<BQ, 256, 0, stream>>>(maskc, refCount, refIdx);
    k_prep<<<BQ * NQ, 128, 0, stream>>>(x, fnh, fnl);
    k_mega<<<GRID_MEGA, 256, 0, stream>>>(fnh, fnl, sim, match);
    k_rowmax<<<dim3(256, BQ), 256, 0, stream>>>(sim, maskc, refCount, refIdx, maxv);
    k_median<<<BQ, 256, 0, stream>>>(maxv, refCount, threshv, outth);
    k_match<<<dim3(256, BQ), 256, 0, stream>>>(sim, maskc, refCount, refIdx, threshv, match);
}